// Round 14
// baseline (184.380 us; speedup 1.0000x reference)
//
#include <hip/hip_runtime.h>

// B=2, S=2048, D=1024, H=16, HD=64. K == Q (xk = x@Wq.T, same RoPE).
// Pipeline: fused f32->bf16 convert -> merged GEMM:
//   [x@Wq.T + RoPE -> Kf frag-layout], [x@Wv.T -> Vf frag-layout]
// -> flash attention, no LDS/barriers in main loop, frag loads coalesced.
// R14: TLP fix. attn block = 32 q-rows, 4 waves = 4-WAY K-SPLIT (not 2),
//   paired subtiles (63-p, p) -> uniform blocks; grid 1024 -> 4096 waves
//   = 4 waves/SIMD (2x R13's TLP). K/V traffic unchanged (k-split is
//   traffic-invariant). 4-way merge via LDS. launch_bounds(256,4).

typedef float f32x4 __attribute__((ext_vector_type(4)));
typedef short s16x8 __attribute__((ext_vector_type(8)));

__device__ inline unsigned short f2bf(float f) {
  union { float f; unsigned u; } v; v.f = f;
  unsigned r = v.u + 0x7FFFu + ((v.u >> 16) & 1u);
  return (unsigned short)(r >> 16);
}

__device__ inline void gload16(const unsigned short* g, unsigned short* l) {
  __builtin_amdgcn_global_load_lds(
      (const __attribute__((address_space(1))) unsigned int*)g,
      (__attribute__((address_space(3))) unsigned int*)l, 16, 0, 0);
}

__global__ __launch_bounds__(256) void convert_all(
    const float* __restrict__ x, const float* __restrict__ wq,
    const float* __restrict__ wv, unsigned short* __restrict__ xb,
    unsigned short* __restrict__ wqb, unsigned short* __restrict__ wvb) {
  int i = blockIdx.x * 256 + threadIdx.x;
  const float* src; unsigned short* dst; int off;
  if (i < 1048576) { src = x; dst = xb; off = i; }
  else if (i < 1310720) { src = wq; dst = wqb; off = i - 1048576; }
  else { src = wv; dst = wvb; off = i - 1310720; }
  float4 v = ((const float4*)src)[off];
  ushort4 o;
  o.x = f2bf(v.x); o.y = f2bf(v.y); o.z = f2bf(v.z); o.w = f2bf(v.w);
  ((ushort4*)dst)[off] = o;
}

// Merged GEMM: grid 512. Blocks [0,256) -> Q-proj (+RoPE) -> Kf.
// Blocks [256,512) -> V-proj -> Vf.  M=4096 N=1024 K=1024, bf16, f32 acc.
__global__ __launch_bounds__(256, 2) void qv_gemm(
    const unsigned short* __restrict__ A, const unsigned short* __restrict__ Wq,
    const unsigned short* __restrict__ Wv, const float* __restrict__ cosT,
    const float* __restrict__ sinT, unsigned short* __restrict__ Kf,
    unsigned short* __restrict__ Vf) {
  __shared__ unsigned short GS[2][2][128][64];  // [buf][A/B][row][col] 64KB
  int tid = threadIdx.x;
  int isq = blockIdx.x < 256;
  int b256 = blockIdx.x & 255;
  int bm = b256 & 31, bn = b256 >> 5;
  int w = tid >> 6, lane = tid & 63, lr = lane & 15, lg = lane >> 4;
  int wm = w >> 1, wn = w & 1;
  int l8 = lane >> 3, l7 = lane & 7;
  f32x4 acc[4][4] = {};

  const unsigned short* Wp = isq ? Wq : Wv;
  const unsigned short* srcbase =
      (w < 2) ? (A + bm * 128 * 1024) : (Wp + bn * 128 * 1024);
  int ab = w >> 1;

  auto stage = [&](int step) {
    int buf = step & 1, kt = step * 64;
#pragma unroll
    for (int i = 0; i < 8; ++i) {
      int rgrp = (w & 1) * 8 + i;
      int u = rgrp * 8 + l8;
      int ch = l7 ^ (u & 7);
      gload16(srcbase + u * 1024 + kt + ch * 8,
              (unsigned short*)&GS[buf][ab][rgrp * 8][0]);
    }
  };

  stage(0);
  for (int step = 0; step < 16; ++step) {
    int buf = step & 1;
    asm volatile("s_waitcnt vmcnt(0)" ::: "memory");
    __syncthreads();
    if (step + 1 < 16) stage(step + 1);
    s16x8 af[4][2], bfr[4][2];
#pragma unroll
    for (int mf = 0; mf < 4; ++mf)
#pragma unroll
      for (int kk = 0; kk < 2; ++kk)
        af[mf][kk] = *(const s16x8*)
            &GS[buf][0][wm * 64 + mf * 16 + lr][((kk * 4 + lg) ^ (lr & 7)) * 8];
#pragma unroll
    for (int nf = 0; nf < 4; ++nf)
#pragma unroll
      for (int kk = 0; kk < 2; ++kk)
        bfr[nf][kk] = *(const s16x8*)
            &GS[buf][1][wn * 64 + nf * 16 + lr][((kk * 4 + lg) ^ (lr & 7)) * 8];
#pragma unroll
    for (int mf = 0; mf < 4; ++mf)
#pragma unroll
      for (int nf = 0; nf < 4; ++nf)
#pragma unroll
        for (int kk = 0; kk < 2; ++kk)
          acc[mf][nf] = __builtin_amdgcn_mfma_f32_16x16x32_bf16(
              af[mf][kk], bfr[nf][kk], acc[mf][nf], 0, 0, 0);
  }

  int mBase = bm * 128 + wm * 64;
  int nBase = bn * 128 + wn * 64;
  if (isq) {
    // RoPE, then per-wave LDS transpose -> coalesced dwordx4 Kf stores.
    __syncthreads();
    unsigned short* Lw = &GS[0][0][0][0] + w * (64 * 72);
    int bq = mBase >> 11;
    int sbase = mBase & 2047;
    int kt = sbase >> 6;
    int h = (nBase >> 6);
    int bh = bq * 16 + h;
#pragma unroll
    for (int mf = 0; mf < 4; ++mf)
#pragma unroll
      for (int j = 0; j < 4; ++j) {
        int sp = mf * 16 + 4 * lg + j;
        int s = sbase + sp;
#pragma unroll
        for (int nf = 0; nf < 4; ++nf) {
          int hd = nf * 16 + lr;
          float self = acc[mf][nf][j];
          float part = (nf < 2) ? -acc[mf][nf + 2][j] : acc[mf][nf - 2][j];
          float val = self * cosT[s * 64 + hd] + part * sinT[s * 64 + hd];
          Lw[sp * 72 + hd] = f2bf(val);
        }
      }
    asm volatile("s_waitcnt lgkmcnt(0)" ::: "memory");
    __builtin_amdgcn_sched_barrier(0);
    unsigned short* KfT = Kf + (size_t)(bh * 32 + kt) * 4096;
#pragma unroll
    for (int i = 0; i < 8; ++i) {
      int kk = i & 1, nfk = i >> 1;
      int lg2 = lane >> 4, lr2 = lane & 15;
      int sp = ((nfk >> 1) << 5) | ((lr2 >> 2) << 3) | ((nfk & 1) << 2) |
               (lr2 & 3);
      int c = kk * 4 + lg2;
      s16x8 vch = *(const s16x8*)&Lw[sp * 72 + c * 8];
      *(s16x8*)&KfT[(i * 64 + lane) * 8] = vch;
    }
  } else {
#pragma unroll
    for (int mf = 0; mf < 4; ++mf) {
      int m0 = mBase + mf * 16 + 4 * lg;
      int b = m0 >> 11, s0 = m0 & 2047;
      int kt = s0 >> 6, w0 = s0 & 63;
      int kkv = w0 >> 5, lg2 = (w0 >> 3) & 3, e0 = w0 & 7;
#pragma unroll
      for (int nf = 0; nf < 4; ++nf) {
        int col = nBase + nf * 16 + lr;
        int h = col >> 6;
        int bh = b * 16 + h;
        ushort4 pk;
        pk.x = f2bf(acc[mf][nf][0]); pk.y = f2bf(acc[mf][nf][1]);
        pk.z = f2bf(acc[mf][nf][2]); pk.w = f2bf(acc[mf][nf][3]);
        int idx2 = (((((bh * 32 + kt) * 4 + nf) * 2 + kkv) * 64) +
                    lg2 * 16 + lr) * 8 + e0;
        *(ushort4*)&Vf[idx2] = pk;
      }
    }
  }
}

// Flash attention: block = 32 q-rows, 4 waves = 4-way k-split (kt = par,
// par+4, ...). grid 1024: XCD-chunked bh x paired 32-row subtiles
// (63-p then p) -> uniform blocks, 4 waves/SIMD TLP. No LDS/barriers in
// main loop; 4-way (m,l,O) merge via LDS after each pass.
__global__ __launch_bounds__(256, 4) void attn(
    const unsigned short* __restrict__ Kf,  // frag layout
    const unsigned short* __restrict__ Vf,  // frag layout
    float* __restrict__ out) {              // [2][2048][1024]
  __shared__ float MB[3][2][4][16][17];     // par 1..3 partial O
  __shared__ float ML[3][2][2][16];         // par 1..3 (m, l)
  const float SC = 0.125f * 1.44269504088896f;  // scale * log2(e)
  const float THR = 44.0f;                      // ~= 8 / SC
  int tid = threadIdx.x;
  int fid = blockIdx.x;
  int bh = 4 * (fid & 7) + ((fid >> 3) & 3);
  int p = fid >> 5;                             // 0..31
  int par = tid >> 6, lane = tid & 63, lr = lane & 15, lg = lane >> 4;
  const unsigned short* KfB = Kf + (size_t)bh * 32 * 4096;
  const unsigned short* VfB = Vf + (size_t)bh * 32 * 4096;
  int b = bh >> 4, h = bh & 15;

  s16x8 kf[4][2], vf[4][2];
  auto loadK = [&](int kt_) {
#pragma unroll
    for (int nf = 0; nf < 4; ++nf)
#pragma unroll
      for (int kk = 0; kk < 2; ++kk)
        kf[nf][kk] = *(const s16x8*)
            &KfB[(((kt_ * 4 + nf) * 2 + kk) * 64 + lane) * 8];
  };
  auto loadV = [&](int kt_) {
#pragma unroll
    for (int nf = 0; nf < 4; ++nf)
#pragma unroll
      for (int kk = 0; kk < 2; ++kk)
        vf[nf][kk] = *(const s16x8*)
            &VfB[(((kt_ * 4 + nf) * 2 + kk) * 64 + lane) * 8];
  };

#pragma unroll 1
  for (int pass = 0; pass < 2; ++pass) {
    int s = pass ? p : (63 - p);   // 32-row subtile index, heavy first
    int q0 = s * 32;
    int ktmax = s >> 1;

    // aq (B-operand) gathered from Kf.
    s16x8 aq[2][2];
#pragma unroll
    for (int qs = 0; qs < 2; ++qs) {
      int qr = q0 + 16 * qs + lr;
      int ktq = qr >> 6, w64 = qr & 63;
      int nfq = ((w64 >> 5) << 1) | ((w64 >> 2) & 1);
      int r31 = w64 & 31;
      int lr2 = ((r31 >> 3) << 2) | (r31 & 3);
#pragma unroll
      for (int kk = 0; kk < 2; ++kk)
        aq[qs][kk] = *(const s16x8*)
            &KfB[((((ktq * 4 + nfq) * 2 + kk) * 64) + lg * 16 + lr2) * 8];
    }

    f32x4 o[2][4] = {};
    float m_[2] = {-1e30f, -1e30f}, l_[2] = {0.f, 0.f};

    int kt = par;
    bool active = kt <= ktmax;
    if (active) { loadK(kt); loadV(kt); }
    while (active) {
      f32x4 sa[2][4];
#pragma unroll
      for (int qs = 0; qs < 2; ++qs)
#pragma unroll
        for (int nf = 0; nf < 4; ++nf) sa[qs][nf] = (f32x4){0.f, 0.f, 0.f, 0.f};
#pragma unroll
      for (int kk = 0; kk < 2; ++kk)
#pragma unroll
        for (int nf = 0; nf < 4; ++nf)
#pragma unroll
          for (int qs = 0; qs < 2; ++qs)
            sa[qs][nf] = __builtin_amdgcn_mfma_f32_16x16x32_bf16(
                kf[nf][kk], aq[qs][kk], sa[qs][nf], 0, 0, 0);

      int ktn = kt + 4;
      bool more = ktn <= ktmax;
      if (more) loadK(ktn);  // pipelined: lands during softmax+PV

      if (kt == ktmax) {     // diag tile: causal mask
#pragma unroll
        for (int qs = 0; qs < 2; ++qs) {
          int qglob = q0 + 16 * qs + lr;
#pragma unroll
          for (int nf = 0; nf < 4; ++nf) {
            int kc = kt * 64 + 8 * lg + 4 * (nf & 1) + 32 * (nf >> 1);
#pragma unroll
            for (int j = 0; j < 4; ++j)
              if (kc + j > qglob) sa[qs][nf][j] = -3e38f;
          }
        }
      }
      float tm[2];
      float worst = -3e38f;
#pragma unroll
      for (int qs = 0; qs < 2; ++qs) {
        float t = sa[qs][0][0];
#pragma unroll
        for (int nf = 0; nf < 4; ++nf)
#pragma unroll
          for (int j = 0; j < 4; ++j) t = fmaxf(t, sa[qs][nf][j]);
        tm[qs] = t;
        worst = fmaxf(worst, t - m_[qs]);
      }
      if (!__all(worst <= THR)) {  // rare after first tile
#pragma unroll
        for (int qs = 0; qs < 2; ++qs) {
          float rm = fmaxf(tm[qs], __shfl_xor(tm[qs], 16));
          rm = fmaxf(rm, __shfl_xor(rm, 32));
          float mn = fmaxf(m_[qs], rm);
          float alpha = exp2f((m_[qs] - mn) * SC);
          m_[qs] = mn; l_[qs] *= alpha;
#pragma unroll
          for (int j = 0; j < 4; ++j) {
            float aj = __shfl(alpha, 4 * lg + j);
#pragma unroll
            for (int nf = 0; nf < 4; ++nf) o[qs][nf][j] *= aj;
          }
        }
      }
      unsigned cpk[2][8];
#pragma unroll
      for (int qs = 0; qs < 2; ++qs) {
        float msc = m_[qs] * SC;
#pragma unroll
        for (int nf = 0; nf < 4; ++nf) {
          float p0 = exp2f(fmaf(sa[qs][nf][0], SC, -msc));
          float p1 = exp2f(fmaf(sa[qs][nf][1], SC, -msc));
          float p2 = exp2f(fmaf(sa[qs][nf][2], SC, -msc));
          float p3 = exp2f(fmaf(sa[qs][nf][3], SC, -msc));
          l_[qs] += (p0 + p1) + (p2 + p3);
          unsigned r0, r1;
          asm("v_cvt_pk_bf16_f32 %0, %1, %2" : "=v"(r0) : "v"(p0), "v"(p1));
          asm("v_cvt_pk_bf16_f32 %0, %1, %2" : "=v"(r1) : "v"(p2), "v"(p3));
          cpk[qs][nf * 2] = r0; cpk[qs][nf * 2 + 1] = r1;
        }
      }
      s16x8 pav[2][2];
#pragma unroll
      for (int qs = 0; qs < 2; ++qs)
#pragma unroll
        for (int kk = 0; kk < 2; ++kk) {
          union { unsigned u[4]; s16x8 v; } pa;
          pa.u[0] = cpk[qs][4 * kk + 0]; pa.u[1] = cpk[qs][4 * kk + 1];
          pa.u[2] = cpk[qs][4 * kk + 2]; pa.u[3] = cpk[qs][4 * kk + 3];
          pav[qs][kk] = pa.v;
        }
#pragma unroll
      for (int kk = 0; kk < 2; ++kk)
#pragma unroll
        for (int nf = 0; nf < 4; ++nf)
#pragma unroll
          for (int qs = 0; qs < 2; ++qs)
            o[qs][nf] = __builtin_amdgcn_mfma_f32_16x16x32_bf16(
                pav[qs][kk], vf[nf][kk], o[qs][nf], 0, 0, 0);
      if (more) loadV(ktn);  // lands during next QK^T+softmax
      kt = ktn; active = more;
    }

    // 4-way merge: par 1..3 publish (m,l,O); par 0 combines + writes out.
#pragma unroll
    for (int qs = 0; qs < 2; ++qs) {
      float t = l_[qs];
      t += __shfl_xor(t, 16); t += __shfl_xor(t, 32);
      l_[qs] = t;
    }
    if (par) {
#pragma unroll
      for (int qs = 0; qs < 2; ++qs) {
#pragma unroll
        for (int nf = 0; nf < 4; ++nf)
#pragma unroll
          for (int j = 0; j < 4; ++j)
            MB[par - 1][qs][nf][4 * lg + j][lr] = o[qs][nf][j];
        if (lg == 0) {
          ML[par - 1][qs][0][lr] = m_[qs];
          ML[par - 1][qs][1][lr] = l_[qs];
        }
      }
    }
    __syncthreads();
    if (par == 0) {
#pragma unroll
      for (int qs = 0; qs < 2; ++qs) {
        float m1 = ML[0][qs][0][lr], l1 = ML[0][qs][1][lr];
        float m2 = ML[1][qs][0][lr], l2 = ML[1][qs][1][lr];
        float m3 = ML[2][qs][0][lr], l3 = ML[2][qs][1][lr];
        float ms = fmaxf(fmaxf(m_[qs], m1), fmaxf(m2, m3));
        float a0 = exp2f((m_[qs] - ms) * SC), a1 = exp2f((m1 - ms) * SC);
        float a2 = exp2f((m2 - ms) * SC), a3 = exp2f((m3 - ms) * SC);
        float inv = 1.0f / (a0 * l_[qs] + a1 * l1 + a2 * l2 + a3 * l3);
#pragma unroll
        for (int j = 0; j < 4; ++j) {
          float c0 = __shfl(a0 * inv, 4 * lg + j);
          float c1 = __shfl(a1 * inv, 4 * lg + j);
          float c2 = __shfl(a2 * inv, 4 * lg + j);
          float c3 = __shfl(a3 * inv, 4 * lg + j);
#pragma unroll
          for (int nf = 0; nf < 4; ++nf) {
            int r = 4 * lg + j;
            float ov = c0 * o[qs][nf][j] + c1 * MB[0][qs][nf][r][lr] +
                       c2 * MB[1][qs][nf][r][lr] + c3 * MB[2][qs][nf][r][lr];
            int q = q0 + 16 * qs + r;
            out[(b * 2048 + q) * 1024 + h * 64 + nf * 16 + lr] = ov;
          }
        }
      }
    }
    __syncthreads();  // MB/ML safe to reuse in next pass
  }
}

extern "C" void kernel_launch(void* const* d_in, const int* in_sizes, int n_in,
                              void* d_out, int out_size, void* d_ws, size_t ws_size,
                              hipStream_t stream) {
  const float* x = (const float*)d_in[0];
  const float* Wq = (const float*)d_in[1];
  const float* Wv = (const float*)d_in[2];
  const float* cosT = (const float*)d_in[3];
  const float* sinT = (const float*)d_in[4];
  float* out = (float*)d_out;

  unsigned short* xb = (unsigned short*)d_ws;        // 4M shorts
  unsigned short* wqb = xb + 4 * 1024 * 1024;        // 1M
  unsigned short* wvb = wqb + 1024 * 1024;           // 1M
  unsigned short* Kfb = wvb + 1024 * 1024;           // 4M (frag-layout RoPE'd Q==K)
  unsigned short* Vfb = Kfb + 4 * 1024 * 1024;       // 4M (frag-layout V)

  convert_all<<<6144, 256, 0, stream>>>(x, Wq, Wv, xb, wqb, wvb);
  qv_gemm<<<512, 256, 0, stream>>>(xb, wqb, wvb, cosT, sinT, Kfb, Vfb);
  attn<<<1024, 256, 0, stream>>>(Kfb, Vfb, out);
}

// Round 15
// 74.838 us; speedup vs baseline: 2.4637x; 2.4637x over previous
//
#include <hip/hip_runtime.h>

// B=2, S=2048, D=1024, H=16, HD=64. K == Q (xk = x@Wq.T, same RoPE).
// Pipeline: fused f32->bf16 convert -> merged GEMM:
//   [x@Wq.T + RoPE -> Kf frag-layout], [x@Wv.T -> Vf frag-layout]
// -> flash attention, no LDS/barriers in main loop, frag loads coalesced.
// R15: R14 structure (32 q-rows/block, 4 waves = 4-way k-split, uniform
//   paired subtiles, grid 1024) with the launch_bounds clamp FIXED:
//   (256,4)->(256,2). R14's VGPR=64 + 424MB spill was the bound, not the
//   structure (Occupancy hit 42%, confirming the TLP mechanism).

typedef float f32x4 __attribute__((ext_vector_type(4)));
typedef short s16x8 __attribute__((ext_vector_type(8)));

__device__ inline unsigned short f2bf(float f) {
  union { float f; unsigned u; } v; v.f = f;
  unsigned r = v.u + 0x7FFFu + ((v.u >> 16) & 1u);
  return (unsigned short)(r >> 16);
}

__device__ inline void gload16(const unsigned short* g, unsigned short* l) {
  __builtin_amdgcn_global_load_lds(
      (const __attribute__((address_space(1))) unsigned int*)g,
      (__attribute__((address_space(3))) unsigned int*)l, 16, 0, 0);
}

__global__ __launch_bounds__(256) void convert_all(
    const float* __restrict__ x, const float* __restrict__ wq,
    const float* __restrict__ wv, unsigned short* __restrict__ xb,
    unsigned short* __restrict__ wqb, unsigned short* __restrict__ wvb) {
  int i = blockIdx.x * 256 + threadIdx.x;
  const float* src; unsigned short* dst; int off;
  if (i < 1048576) { src = x; dst = xb; off = i; }
  else if (i < 1310720) { src = wq; dst = wqb; off = i - 1048576; }
  else { src = wv; dst = wvb; off = i - 1310720; }
  float4 v = ((const float4*)src)[off];
  ushort4 o;
  o.x = f2bf(v.x); o.y = f2bf(v.y); o.z = f2bf(v.z); o.w = f2bf(v.w);
  ((ushort4*)dst)[off] = o;
}

// Merged GEMM: grid 512. Blocks [0,256) -> Q-proj (+RoPE) -> Kf.
// Blocks [256,512) -> V-proj -> Vf.  M=4096 N=1024 K=1024, bf16, f32 acc.
__global__ __launch_bounds__(256, 2) void qv_gemm(
    const unsigned short* __restrict__ A, const unsigned short* __restrict__ Wq,
    const unsigned short* __restrict__ Wv, const float* __restrict__ cosT,
    const float* __restrict__ sinT, unsigned short* __restrict__ Kf,
    unsigned short* __restrict__ Vf) {
  __shared__ unsigned short GS[2][2][128][64];  // [buf][A/B][row][col] 64KB
  int tid = threadIdx.x;
  int isq = blockIdx.x < 256;
  int b256 = blockIdx.x & 255;
  int bm = b256 & 31, bn = b256 >> 5;
  int w = tid >> 6, lane = tid & 63, lr = lane & 15, lg = lane >> 4;
  int wm = w >> 1, wn = w & 1;
  int l8 = lane >> 3, l7 = lane & 7;
  f32x4 acc[4][4] = {};

  const unsigned short* Wp = isq ? Wq : Wv;
  const unsigned short* srcbase =
      (w < 2) ? (A + bm * 128 * 1024) : (Wp + bn * 128 * 1024);
  int ab = w >> 1;

  auto stage = [&](int step) {
    int buf = step & 1, kt = step * 64;
#pragma unroll
    for (int i = 0; i < 8; ++i) {
      int rgrp = (w & 1) * 8 + i;
      int u = rgrp * 8 + l8;
      int ch = l7 ^ (u & 7);
      gload16(srcbase + u * 1024 + kt + ch * 8,
              (unsigned short*)&GS[buf][ab][rgrp * 8][0]);
    }
  };

  stage(0);
  for (int step = 0; step < 16; ++step) {
    int buf = step & 1;
    asm volatile("s_waitcnt vmcnt(0)" ::: "memory");
    __syncthreads();
    if (step + 1 < 16) stage(step + 1);
    s16x8 af[4][2], bfr[4][2];
#pragma unroll
    for (int mf = 0; mf < 4; ++mf)
#pragma unroll
      for (int kk = 0; kk < 2; ++kk)
        af[mf][kk] = *(const s16x8*)
            &GS[buf][0][wm * 64 + mf * 16 + lr][((kk * 4 + lg) ^ (lr & 7)) * 8];
#pragma unroll
    for (int nf = 0; nf < 4; ++nf)
#pragma unroll
      for (int kk = 0; kk < 2; ++kk)
        bfr[nf][kk] = *(const s16x8*)
            &GS[buf][1][wn * 64 + nf * 16 + lr][((kk * 4 + lg) ^ (lr & 7)) * 8];
#pragma unroll
    for (int mf = 0; mf < 4; ++mf)
#pragma unroll
      for (int nf = 0; nf < 4; ++nf)
#pragma unroll
        for (int kk = 0; kk < 2; ++kk)
          acc[mf][nf] = __builtin_amdgcn_mfma_f32_16x16x32_bf16(
              af[mf][kk], bfr[nf][kk], acc[mf][nf], 0, 0, 0);
  }

  int mBase = bm * 128 + wm * 64;
  int nBase = bn * 128 + wn * 64;
  if (isq) {
    // RoPE, then per-wave LDS transpose -> coalesced dwordx4 Kf stores.
    __syncthreads();
    unsigned short* Lw = &GS[0][0][0][0] + w * (64 * 72);
    int bq = mBase >> 11;
    int sbase = mBase & 2047;
    int kt = sbase >> 6;
    int h = (nBase >> 6);
    int bh = bq * 16 + h;
#pragma unroll
    for (int mf = 0; mf < 4; ++mf)
#pragma unroll
      for (int j = 0; j < 4; ++j) {
        int sp = mf * 16 + 4 * lg + j;
        int s = sbase + sp;
#pragma unroll
        for (int nf = 0; nf < 4; ++nf) {
          int hd = nf * 16 + lr;
          float self = acc[mf][nf][j];
          float part = (nf < 2) ? -acc[mf][nf + 2][j] : acc[mf][nf - 2][j];
          float val = self * cosT[s * 64 + hd] + part * sinT[s * 64 + hd];
          Lw[sp * 72 + hd] = f2bf(val);
        }
      }
    asm volatile("s_waitcnt lgkmcnt(0)" ::: "memory");
    __builtin_amdgcn_sched_barrier(0);
    unsigned short* KfT = Kf + (size_t)(bh * 32 + kt) * 4096;
#pragma unroll
    for (int i = 0; i < 8; ++i) {
      int kk = i & 1, nfk = i >> 1;
      int lg2 = lane >> 4, lr2 = lane & 15;
      int sp = ((nfk >> 1) << 5) | ((lr2 >> 2) << 3) | ((nfk & 1) << 2) |
               (lr2 & 3);
      int c = kk * 4 + lg2;
      s16x8 vch = *(const s16x8*)&Lw[sp * 72 + c * 8];
      *(s16x8*)&KfT[(i * 64 + lane) * 8] = vch;
    }
  } else {
#pragma unroll
    for (int mf = 0; mf < 4; ++mf) {
      int m0 = mBase + mf * 16 + 4 * lg;
      int b = m0 >> 11, s0 = m0 & 2047;
      int kt = s0 >> 6, w0 = s0 & 63;
      int kkv = w0 >> 5, lg2 = (w0 >> 3) & 3, e0 = w0 & 7;
#pragma unroll
      for (int nf = 0; nf < 4; ++nf) {
        int col = nBase + nf * 16 + lr;
        int h = col >> 6;
        int bh = b * 16 + h;
        ushort4 pk;
        pk.x = f2bf(acc[mf][nf][0]); pk.y = f2bf(acc[mf][nf][1]);
        pk.z = f2bf(acc[mf][nf][2]); pk.w = f2bf(acc[mf][nf][3]);
        int idx2 = (((((bh * 32 + kt) * 4 + nf) * 2 + kkv) * 64) +
                    lg2 * 16 + lr) * 8 + e0;
        *(ushort4*)&Vf[idx2] = pk;
      }
    }
  }
}

// Flash attention: block = 32 q-rows, 4 waves = 4-way k-split (kt = par,
// par+4, ...). grid 1024: XCD-chunked bh x paired 32-row subtiles
// (63-p then p) -> uniform blocks (33 tiles each). No LDS/barriers in
// main loop; 4-way (m,l,O) merge via LDS after each pass.
__global__ __launch_bounds__(256, 2) void attn(
    const unsigned short* __restrict__ Kf,  // frag layout
    const unsigned short* __restrict__ Vf,  // frag layout
    float* __restrict__ out) {              // [2][2048][1024]
  __shared__ float MB[3][2][4][16][17];     // par 1..3 partial O
  __shared__ float ML[3][2][2][16];         // par 1..3 (m, l)
  const float SC = 0.125f * 1.44269504088896f;  // scale * log2(e)
  const float THR = 44.0f;                      // ~= 8 / SC
  int tid = threadIdx.x;
  int fid = blockIdx.x;
  int bh = 4 * (fid & 7) + ((fid >> 3) & 3);
  int p = fid >> 5;                             // 0..31
  int par = tid >> 6, lane = tid & 63, lr = lane & 15, lg = lane >> 4;
  const unsigned short* KfB = Kf + (size_t)bh * 32 * 4096;
  const unsigned short* VfB = Vf + (size_t)bh * 32 * 4096;
  int b = bh >> 4, h = bh & 15;

  s16x8 kf[4][2], vf[4][2];
  auto loadK = [&](int kt_) {
#pragma unroll
    for (int nf = 0; nf < 4; ++nf)
#pragma unroll
      for (int kk = 0; kk < 2; ++kk)
        kf[nf][kk] = *(const s16x8*)
            &KfB[(((kt_ * 4 + nf) * 2 + kk) * 64 + lane) * 8];
  };
  auto loadV = [&](int kt_) {
#pragma unroll
    for (int nf = 0; nf < 4; ++nf)
#pragma unroll
      for (int kk = 0; kk < 2; ++kk)
        vf[nf][kk] = *(const s16x8*)
            &VfB[(((kt_ * 4 + nf) * 2 + kk) * 64 + lane) * 8];
  };

#pragma unroll 1
  for (int pass = 0; pass < 2; ++pass) {
    int s = pass ? p : (63 - p);   // 32-row subtile index, heavy first
    int q0 = s * 32;
    int ktmax = s >> 1;

    // aq (B-operand) gathered from Kf.
    s16x8 aq[2][2];
#pragma unroll
    for (int qs = 0; qs < 2; ++qs) {
      int qr = q0 + 16 * qs + lr;
      int ktq = qr >> 6, w64 = qr & 63;
      int nfq = ((w64 >> 5) << 1) | ((w64 >> 2) & 1);
      int r31 = w64 & 31;
      int lr2 = ((r31 >> 3) << 2) | (r31 & 3);
#pragma unroll
      for (int kk = 0; kk < 2; ++kk)
        aq[qs][kk] = *(const s16x8*)
            &KfB[((((ktq * 4 + nfq) * 2 + kk) * 64) + lg * 16 + lr2) * 8];
    }

    f32x4 o[2][4] = {};
    float m_[2] = {-1e30f, -1e30f}, l_[2] = {0.f, 0.f};

    int kt = par;
    bool active = kt <= ktmax;
    if (active) { loadK(kt); loadV(kt); }
    while (active) {
      f32x4 sa[2][4];
#pragma unroll
      for (int qs = 0; qs < 2; ++qs)
#pragma unroll
        for (int nf = 0; nf < 4; ++nf) sa[qs][nf] = (f32x4){0.f, 0.f, 0.f, 0.f};
#pragma unroll
      for (int kk = 0; kk < 2; ++kk)
#pragma unroll
        for (int nf = 0; nf < 4; ++nf)
#pragma unroll
          for (int qs = 0; qs < 2; ++qs)
            sa[qs][nf] = __builtin_amdgcn_mfma_f32_16x16x32_bf16(
                kf[nf][kk], aq[qs][kk], sa[qs][nf], 0, 0, 0);

      int ktn = kt + 4;
      bool more = ktn <= ktmax;
      if (more) loadK(ktn);  // pipelined: lands during softmax+PV

      if (kt == ktmax) {     // diag tile: causal mask
#pragma unroll
        for (int qs = 0; qs < 2; ++qs) {
          int qglob = q0 + 16 * qs + lr;
#pragma unroll
          for (int nf = 0; nf < 4; ++nf) {
            int kc = kt * 64 + 8 * lg + 4 * (nf & 1) + 32 * (nf >> 1);
#pragma unroll
            for (int j = 0; j < 4; ++j)
              if (kc + j > qglob) sa[qs][nf][j] = -3e38f;
          }
        }
      }
      float tm[2];
      float worst = -3e38f;
#pragma unroll
      for (int qs = 0; qs < 2; ++qs) {
        float t = sa[qs][0][0];
#pragma unroll
        for (int nf = 0; nf < 4; ++nf)
#pragma unroll
          for (int j = 0; j < 4; ++j) t = fmaxf(t, sa[qs][nf][j]);
        tm[qs] = t;
        worst = fmaxf(worst, t - m_[qs]);
      }
      if (!__all(worst <= THR)) {  // rare after first tile
#pragma unroll
        for (int qs = 0; qs < 2; ++qs) {
          float rm = fmaxf(tm[qs], __shfl_xor(tm[qs], 16));
          rm = fmaxf(rm, __shfl_xor(rm, 32));
          float mn = fmaxf(m_[qs], rm);
          float alpha = exp2f((m_[qs] - mn) * SC);
          m_[qs] = mn; l_[qs] *= alpha;
#pragma unroll
          for (int j = 0; j < 4; ++j) {
            float aj = __shfl(alpha, 4 * lg + j);
#pragma unroll
            for (int nf = 0; nf < 4; ++nf) o[qs][nf][j] *= aj;
          }
        }
      }
      unsigned cpk[2][8];
#pragma unroll
      for (int qs = 0; qs < 2; ++qs) {
        float msc = m_[qs] * SC;
#pragma unroll
        for (int nf = 0; nf < 4; ++nf) {
          float p0 = exp2f(fmaf(sa[qs][nf][0], SC, -msc));
          float p1 = exp2f(fmaf(sa[qs][nf][1], SC, -msc));
          float p2 = exp2f(fmaf(sa[qs][nf][2], SC, -msc));
          float p3 = exp2f(fmaf(sa[qs][nf][3], SC, -msc));
          l_[qs] += (p0 + p1) + (p2 + p3);
          unsigned r0, r1;
          asm("v_cvt_pk_bf16_f32 %0, %1, %2" : "=v"(r0) : "v"(p0), "v"(p1));
          asm("v_cvt_pk_bf16_f32 %0, %1, %2" : "=v"(r1) : "v"(p2), "v"(p3));
          cpk[qs][nf * 2] = r0; cpk[qs][nf * 2 + 1] = r1;
        }
      }
      s16x8 pav[2][2];
#pragma unroll
      for (int qs = 0; qs < 2; ++qs)
#pragma unroll
        for (int kk = 0; kk < 2; ++kk) {
          union { unsigned u[4]; s16x8 v; } pa;
          pa.u[0] = cpk[qs][4 * kk + 0]; pa.u[1] = cpk[qs][4 * kk + 1];
          pa.u[2] = cpk[qs][4 * kk + 2]; pa.u[3] = cpk[qs][4 * kk + 3];
          pav[qs][kk] = pa.v;
        }
#pragma unroll
      for (int kk = 0; kk < 2; ++kk)
#pragma unroll
        for (int nf = 0; nf < 4; ++nf)
#pragma unroll
          for (int qs = 0; qs < 2; ++qs)
            o[qs][nf] = __builtin_amdgcn_mfma_f32_16x16x32_bf16(
                pav[qs][kk], vf[nf][kk], o[qs][nf], 0, 0, 0);
      if (more) loadV(ktn);  // lands during next QK^T+softmax
      kt = ktn; active = more;
    }

    // 4-way merge: par 1..3 publish (m,l,O); par 0 combines + writes out.
#pragma unroll
    for (int qs = 0; qs < 2; ++qs) {
      float t = l_[qs];
      t += __shfl_xor(t, 16); t += __shfl_xor(t, 32);
      l_[qs] = t;
    }
    if (par) {
#pragma unroll
      for (int qs = 0; qs < 2; ++qs) {
#pragma unroll
        for (int nf = 0; nf < 4; ++nf)
#pragma unroll
          for (int j = 0; j < 4; ++j)
            MB[par - 1][qs][nf][4 * lg + j][lr] = o[qs][nf][j];
        if (lg == 0) {
          ML[par - 1][qs][0][lr] = m_[qs];
          ML[par - 1][qs][1][lr] = l_[qs];
        }
      }
    }
    __syncthreads();
    if (par == 0) {
#pragma unroll
      for (int qs = 0; qs < 2; ++qs) {
        float m1 = ML[0][qs][0][lr], l1 = ML[0][qs][1][lr];
        float m2 = ML[1][qs][0][lr], l2 = ML[1][qs][1][lr];
        float m3 = ML[2][qs][0][lr], l3 = ML[2][qs][1][lr];
        float ms = fmaxf(fmaxf(m_[qs], m1), fmaxf(m2, m3));
        float a0 = exp2f((m_[qs] - ms) * SC), a1 = exp2f((m1 - ms) * SC);
        float a2 = exp2f((m2 - ms) * SC), a3 = exp2f((m3 - ms) * SC);
        float inv = 1.0f / (a0 * l_[qs] + a1 * l1 + a2 * l2 + a3 * l3);
#pragma unroll
        for (int j = 0; j < 4; ++j) {
          float c0 = __shfl(a0 * inv, 4 * lg + j);
          float c1 = __shfl(a1 * inv, 4 * lg + j);
          float c2 = __shfl(a2 * inv, 4 * lg + j);
          float c3 = __shfl(a3 * inv, 4 * lg + j);
#pragma unroll
          for (int nf = 0; nf < 4; ++nf) {
            int r = 4 * lg + j;
            float ov = c0 * o[qs][nf][j] + c1 * MB[0][qs][nf][r][lr] +
                       c2 * MB[1][qs][nf][r][lr] + c3 * MB[2][qs][nf][r][lr];
            int q = q0 + 16 * qs + r;
            out[(b * 2048 + q) * 1024 + h * 64 + nf * 16 + lr] = ov;
          }
        }
      }
    }
    __syncthreads();  // MB/ML safe to reuse in next pass
  }
}

extern "C" void kernel_launch(void* const* d_in, const int* in_sizes, int n_in,
                              void* d_out, int out_size, void* d_ws, size_t ws_size,
                              hipStream_t stream) {
  const float* x = (const float*)d_in[0];
  const float* Wq = (const float*)d_in[1];
  const float* Wv = (const float*)d_in[2];
  const float* cosT = (const float*)d_in[3];
  const float* sinT = (const float*)d_in[4];
  float* out = (float*)d_out;

  unsigned short* xb = (unsigned short*)d_ws;        // 4M shorts
  unsigned short* wqb = xb + 4 * 1024 * 1024;        // 1M
  unsigned short* wvb = wqb + 1024 * 1024;           // 1M
  unsigned short* Kfb = wvb + 1024 * 1024;           // 4M (frag-layout RoPE'd Q==K)
  unsigned short* Vfb = Kfb + 4 * 1024 * 1024;       // 4M (frag-layout V)

  convert_all<<<6144, 256, 0, stream>>>(x, Wq, Wv, xb, wqb, wvb);
  qv_gemm<<<512, 256, 0, stream>>>(xb, wqb, wvb, cosT, sinT, Kfb, Vfb);
  attn<<<1024, 256, 0, stream>>>(Kfb, Vfb, out);
}